// Round 5
// baseline (5771.704 us; speedup 1.0000x reference)
//
#include <hip/hip_runtime.h>

// GRU: B=32, S=512, D=1024, H=1024
// out = concat(output[B,S,H], h_last[B,H]) f32
#define B_  32
#define S_  512
#define D_  1024
#define H_  1024
#define G3  3072

typedef __attribute__((ext_vector_type(8))) short  short8;   // 8 x bf16 (4 VGPR)
typedef __attribute__((ext_vector_type(4))) float  floatx4;  // MFMA C/D

__device__ __forceinline__ unsigned short f2bf(float f) {
    unsigned int u = __builtin_bit_cast(unsigned int, f);
    u = (u + 0x7FFFu + ((u >> 16) & 1u)) >> 16;
    return (unsigned short)u;
}
__device__ __forceinline__ float bf2f(unsigned short h) {
    unsigned int u = ((unsigned int)h) << 16;
    return __builtin_bit_cast(float, u);
}
// fast sigmoid/tanh via v_exp_f32 + v_rcp_f32 (saturate correctly at +/-inf)
__device__ __forceinline__ float fsigmoid(float x) {
    float e = __builtin_amdgcn_exp2f(-1.4426950408889634f * x);
    return __builtin_amdgcn_rcpf(1.f + e);
}
__device__ __forceinline__ float ftanh(float x) {
    float e = __builtin_amdgcn_exp2f(2.8853900817779268f * x);
    return 1.f - 2.f * __builtin_amdgcn_rcpf(e + 1.f);
}

// ---------------------------------------------------------------------------
// Kernel 0: convert weights f32->bf16 (W_hh hi/lo split), zero tagged h buf
// ---------------------------------------------------------------------------
__global__ __launch_bounds__(256) void convert_kernel(
    const float* __restrict__ wih, const float* __restrict__ whh,
    unsigned short* __restrict__ wih_h,
    unsigned short* __restrict__ whh_h, unsigned short* __restrict__ whh_l,
    unsigned int* __restrict__ hbuf /* 131072 uints: 2 x 32 x 1024 u64 */) {
    int tid = blockIdx.x * 256 + threadIdx.x;   // 786432 threads
    int i4 = tid * 4;
    if (i4 < 3145728) {
        float4 w = *(const float4*)(wih + i4);
        ushort4 o;
        o.x = f2bf(w.x); o.y = f2bf(w.y); o.z = f2bf(w.z); o.w = f2bf(w.w);
        *(ushort4*)(wih_h + i4) = o;

        float4 v = *(const float4*)(whh + i4);
        ushort4 h;
        h.x = f2bf(v.x); h.y = f2bf(v.y); h.z = f2bf(v.z); h.w = f2bf(v.w);
        ushort4 l;
        l.x = f2bf(v.x - bf2f(h.x)); l.y = f2bf(v.y - bf2f(h.y));
        l.z = f2bf(v.z - bf2f(h.z)); l.w = f2bf(v.w - bf2f(h.w));
        *(ushort4*)(whh_h + i4) = h;
        *(ushort4*)(whh_l + i4) = l;
    }
    if (tid < 32768) {  // zero both tagged h ping-pong buffers (tag0|data0 = h0)
        uint4 z; z.x = z.y = z.z = z.w = 0;
        *(uint4*)(hbuf + tid * 4) = z;
    }
}

// ---------------------------------------------------------------------------
// Kernel 1: gi = feats @ W_ih^T + bias_ih   -> bf16 [B*S][3H]  (unchanged)
// ---------------------------------------------------------------------------
#define BM 128
#define BN 128
#define BK 32
#define LDA 40  // padded LDS row: 80B stride -> conflict-free b128 reads

__global__ __launch_bounds__(256, 2) void gi_gemm(
    const float* __restrict__ feats,
    const unsigned short* __restrict__ wih_h,
    const float* __restrict__ bias_ih,
    unsigned short* __restrict__ gi) {
    __shared__ unsigned short As[BM * LDA];
    __shared__ unsigned short Bs[BN * LDA];

    int bx = blockIdx.x;
    int nb = bx % (G3 / BN);          // 24
    int mb = bx / (G3 / BN);          // 128
    int m0 = mb * BM, n0 = nb * BN;
    int tid = threadIdx.x;
    int lane = tid & 63, wave = tid >> 6;
    int quad = lane >> 4, l15 = lane & 15;
    int wm = (wave >> 1) * 64, wn = (wave & 1) * 64;

    floatx4 acc[4][4];
#pragma unroll
    for (int i = 0; i < 4; ++i)
#pragma unroll
        for (int j = 0; j < 4; ++j) acc[i][j] = (floatx4){0.f, 0.f, 0.f, 0.f};

    float bias[4];
#pragma unroll
    for (int j = 0; j < 4; ++j) bias[j] = bias_ih[n0 + wn + j * 16 + l15];

    int srow = tid >> 1, shalf = tid & 1;
    const float* aptr = feats + (size_t)(m0 + srow) * D_ + shalf * 16;
    const unsigned short* bptr = wih_h + (size_t)(n0 + srow) * D_ + shalf * 16;
    unsigned short* as = As + srow * LDA + shalf * 16;
    unsigned short* bs = Bs + srow * LDA + shalf * 16;

    for (int kt = 0; kt < D_ / BK; ++kt) {
        int k0 = kt * BK;
        float4 a0 = *(const float4*)(aptr + k0);
        float4 a1 = *(const float4*)(aptr + k0 + 4);
        float4 a2 = *(const float4*)(aptr + k0 + 8);
        float4 a3 = *(const float4*)(aptr + k0 + 12);
        uint4 bA = *(const uint4*)(bptr + k0);
        uint4 bB = *(const uint4*)(bptr + k0 + 8);

        union { unsigned short u16[16]; uint4 v[2]; } pk;
        pk.u16[0] = f2bf(a0.x);  pk.u16[1] = f2bf(a0.y);
        pk.u16[2] = f2bf(a0.z);  pk.u16[3] = f2bf(a0.w);
        pk.u16[4] = f2bf(a1.x);  pk.u16[5] = f2bf(a1.y);
        pk.u16[6] = f2bf(a1.z);  pk.u16[7] = f2bf(a1.w);
        pk.u16[8] = f2bf(a2.x);  pk.u16[9] = f2bf(a2.y);
        pk.u16[10] = f2bf(a2.z); pk.u16[11] = f2bf(a2.w);
        pk.u16[12] = f2bf(a3.x); pk.u16[13] = f2bf(a3.y);
        pk.u16[14] = f2bf(a3.z); pk.u16[15] = f2bf(a3.w);

        *(uint4*)as = pk.v[0];
        *(uint4*)(as + 8) = pk.v[1];
        *(uint4*)bs = bA;
        *(uint4*)(bs + 8) = bB;
        __syncthreads();

        short8 af[4], bf[4];
#pragma unroll
        for (int i = 0; i < 4; ++i)
            af[i] = *(const short8*)(As + (wm + i * 16 + l15) * LDA + quad * 8);
#pragma unroll
        for (int j = 0; j < 4; ++j)
            bf[j] = *(const short8*)(Bs + (wn + j * 16 + l15) * LDA + quad * 8);
#pragma unroll
        for (int i = 0; i < 4; ++i)
#pragma unroll
            for (int j = 0; j < 4; ++j)
                acc[i][j] = __builtin_amdgcn_mfma_f32_16x16x32_bf16(
                    af[i], bf[j], acc[i][j], 0, 0, 0);
        __syncthreads();
    }

#pragma unroll
    for (int i = 0; i < 4; ++i)
#pragma unroll
        for (int j = 0; j < 4; ++j)
#pragma unroll
            for (int r = 0; r < 4; ++r) {
                int m = m0 + wm + i * 16 + quad * 4 + r;
                int n = n0 + wn + j * 16 + l15;
                gi[(size_t)m * G3 + n] = f2bf(acc[i][j][r] + bias[j]);
            }
}

// ---------------------------------------------------------------------------
// Kernel 2: persistent recurrence — TAG-IN-DATA protocol (no flags, no
// drains). h element = u64: (tag = step)<<32 | (hi_bf16 | lo_bf16<<16).
// 8B aligned atomic stores carry data+tag together; consumers poll the
// data itself (per-wave, no barrier #1). Ping-pong by parity + exact tag
// match is race-free (2-deep pipeline argument). Finish spread over 256
// lanes (1 output each). Everything else = verified round-4 shell.
// ---------------------------------------------------------------------------
__global__ __launch_bounds__(512, 2) void gru_rec(
    const unsigned short* __restrict__ gi,
    const unsigned short* __restrict__ whh_h,
    const unsigned short* __restrict__ whh_l,
    const float* __restrict__ bias_hh,
    unsigned long long* __restrict__ hbuf,  // [2][32][1024] u64 tagged
    float* __restrict__ out) {
    __shared__ floatx4 parts[8][3][64];  // 24 KB

    const int tid = threadIdx.x;
    const int lane = tid & 63, ks = tid >> 6;
    const int quad = lane >> 4, l15 = lane & 15;
    const int jg = blockIdx.x >> 1, mt = blockIdx.x & 1;
    const int j = jg * 16 + l15;

    // preload W_hh fragments (hi+lo): 3 gates x 4 ksteps x 16B = 96 VGPRs
    short8 wfh[3][4], wfl[3][4];
#pragma unroll
    for (int g = 0; g < 3; ++g)
#pragma unroll
        for (int ki = 0; ki < 4; ++ki) {
            size_t off = (size_t)(g * H_ + j) * H_ + ks * 128 + ki * 32 + quad * 8;
            wfh[g][ki] = *(const short8*)(whh_h + off);
            wfl[g][ki] = *(const short8*)(whh_l + off);
        }

    // finish mapping (tid<256): one output (row rr, col cc) per lane
    const int rr = (tid >> 4) & 15, cc = tid & 15;
    const int brow = mt * 16 + rr;
    const int jc = jg * 16 + cc;
    float bR = 0.f, bZ = 0.f, bN = 0.f, hreg = 0.f;
    unsigned short giR = 0, giZ = 0, giN = 0;
    if (tid < 256) {
        bR = bias_hh[jc]; bZ = bias_hh[H_ + jc]; bN = bias_hh[2 * H_ + jc];
        const size_t gb = (size_t)brow * S_ * G3 + jc;
        giR = gi[gb]; giZ = gi[gb + H_]; giN = gi[gb + 2 * H_];
    }

    // this lane's h slice: row arow, cols ks*128 + quad*8 + ki*32 + c
    const int arow = mt * 16 + l15;
    const size_t lslice = (size_t)arow * 1024 + ks * 128 + quad * 8;
    const float* const pf = (const float*)parts;

    for (int t = 0; t < S_; ++t) {
        const unsigned long long* hp = hbuf + ((size_t)(t & 1) << 15) + lslice;
        const unsigned int want = (unsigned int)t;

        short8 ah[4], al[4];
        // ---- phase A: poll+load ki 0..1 (16 u64), tags must equal t ----
        {
            unsigned long long q[16];
            int ok;
            do {
#pragma unroll
                for (int ki = 0; ki < 2; ++ki)
#pragma unroll
                    for (int c = 0; c < 8; ++c)
                        q[ki * 8 + c] = __hip_atomic_load(hp + ki * 32 + c,
                                                          __ATOMIC_RELAXED,
                                                          __HIP_MEMORY_SCOPE_AGENT);
                ok = 1;
#pragma unroll
                for (int i = 0; i < 16; ++i)
                    ok &= ((unsigned int)(q[i] >> 32) == want);
            } while (!__all(ok));
#pragma unroll
            for (int ki = 0; ki < 2; ++ki) {
                short8 av, lv;
#pragma unroll
                for (int c = 0; c < 8; ++c) {
                    unsigned int d = (unsigned int)q[ki * 8 + c];
                    av[c] = (short)(d & 0xffffu);
                    lv[c] = (short)(d >> 16);
                }
                ah[ki] = av; al[ki] = lv;
            }
        }
        // ---- phase B: poll+load ki 2..3 ----
        {
            unsigned long long q[16];
            int ok;
            do {
#pragma unroll
                for (int ki = 0; ki < 2; ++ki)
#pragma unroll
                    for (int c = 0; c < 8; ++c)
                        q[ki * 8 + c] = __hip_atomic_load(hp + (ki + 2) * 32 + c,
                                                          __ATOMIC_RELAXED,
                                                          __HIP_MEMORY_SCOPE_AGENT);
                ok = 1;
#pragma unroll
                for (int i = 0; i < 16; ++i)
                    ok &= ((unsigned int)(q[i] >> 32) == want);
            } while (!__all(ok));
#pragma unroll
            for (int ki = 0; ki < 2; ++ki) {
                short8 av, lv;
#pragma unroll
                for (int c = 0; c < 8; ++c) {
                    unsigned int d = (unsigned int)q[ki * 8 + c];
                    av[c] = (short)(d & 0xffffu);
                    lv[c] = (short)(d >> 16);
                }
                ah[ki + 2] = av; al[ki + 2] = lv;
            }
        }

        // gi prefetch for t+1: issued now so HBM latency hides under
        // MFMA + reduce + gates (not under the next poll wait)
        unsigned short nR = 0, nZ = 0, nN = 0;
        if (tid < 256 && t + 1 < S_) {
            const size_t gb = ((size_t)brow * S_ + (t + 1)) * G3 + jc;
            nR = gi[gb]; nZ = gi[gb + H_]; nN = gi[gb + 2 * H_];
        }

        floatx4 acc[3];
#pragma unroll
        for (int g = 0; g < 3; ++g) acc[g] = (floatx4){0.f, 0.f, 0.f, 0.f};
#pragma unroll
        for (int ki = 0; ki < 4; ++ki)
#pragma unroll
            for (int g = 0; g < 3; ++g) {
                acc[g] = __builtin_amdgcn_mfma_f32_16x16x32_bf16(ah[ki], wfh[g][ki], acc[g], 0, 0, 0);
                acc[g] = __builtin_amdgcn_mfma_f32_16x16x32_bf16(ah[ki], wfl[g][ki], acc[g], 0, 0, 0);
                acc[g] = __builtin_amdgcn_mfma_f32_16x16x32_bf16(al[ki], wfh[g][ki], acc[g], 0, 0, 0);
            }
#pragma unroll
        for (int g = 0; g < 3; ++g) parts[ks][g][lane] = acc[g];
        __syncthreads();   // #2: parts visible to finish lanes

        float gh0 = 0.f, gh1 = 0.f, gh2 = 0.f;
        if (tid < 256) {   // reduce: element (row rr, col cc)
            const int vidx = ((rr >> 2) * 16 + cc) * 4 + (rr & 3);
#pragma unroll
            for (int w = 0; w < 8; ++w) {
                gh0 += pf[((w * 3 + 0) * 64) * 4 + vidx];
                gh1 += pf[((w * 3 + 1) * 64) * 4 + vidx];
                gh2 += pf[((w * 3 + 2) * 64) * 4 + vidx];
            }
        }
        __syncthreads();   // #3: parts consumed; next-iter writes are safe

        if (tid < 256) {
            const float rg = fsigmoid(bf2f(giR) + gh0 + bR);
            const float zg = fsigmoid(bf2f(giZ) + gh1 + bZ);
            const float ng = ftanh(bf2f(giN) + rg * (gh2 + bN));
            const float hy = ng + zg * (hreg - ng);
            hreg = hy;
            const unsigned short hh = f2bf(hy);
            const unsigned int pk = (unsigned int)hh |
                                    ((unsigned int)f2bf(hy - bf2f(hh)) << 16);
            const unsigned long long hv =
                ((unsigned long long)(unsigned int)(t + 1) << 32) |
                (unsigned long long)pk;
            // fire-and-forget: tag+data land atomically, no drain, no flag
            __hip_atomic_store(hbuf + ((size_t)((t + 1) & 1) << 15) +
                               (size_t)brow * 1024 + jc,
                               hv, __ATOMIC_RELAXED, __HIP_MEMORY_SCOPE_AGENT);
            __builtin_nontemporal_store(hy, out + ((size_t)brow * S_ + t) * H_ + jc);
            if (t == S_ - 1)
                __builtin_nontemporal_store(hy,
                    out + (size_t)B_ * S_ * H_ + (size_t)brow * H_ + jc);
        }
        giR = nR; giZ = nZ; giN = nN;
    }
}

// ---------------------------------------------------------------------------
extern "C" void kernel_launch(void* const* d_in, const int* in_sizes, int n_in,
                              void* d_out, int out_size, void* d_ws, size_t ws_size,
                              hipStream_t stream) {
    const float* feats = (const float*)d_in[0];
    const float* wih   = (const float*)d_in[1];
    const float* whh   = (const float*)d_in[2];
    const float* bih   = (const float*)d_in[3];
    const float* bhh   = (const float*)d_in[4];
    float* out = (float*)d_out;

    // ws layout (ushorts): wih_h | whh_h | whh_l | gi | hbuf(u64 tagged)
    unsigned short* wih_h = (unsigned short*)d_ws;
    unsigned short* whh_h = wih_h + (size_t)3145728;
    unsigned short* whh_l = whh_h + (size_t)3145728;
    unsigned short* gi    = whh_l + (size_t)3145728;
    unsigned long long* hbuf = (unsigned long long*)(gi + (size_t)16384 * G3);

    hipLaunchKernelGGL(convert_kernel, dim3(3072), dim3(256), 0, stream,
                       wih, whh, wih_h, whh_h, whh_l, (unsigned int*)hbuf);
    hipLaunchKernelGGL(gi_gemm, dim3(3072), dim3(256), 0, stream,
                       feats, wih_h, bih, gi);

    void* args[] = {(void*)&gi, (void*)&whh_h, (void*)&whh_l,
                    (void*)&bhh, (void*)&hbuf, (void*)&out};
    hipLaunchCooperativeKernel((const void*)gru_rec, dim3(128), dim3(512),
                               args, 0, stream);
}

// Round 6
// 5248.297 us; speedup vs baseline: 1.0997x; 1.0997x over previous
//
#include <hip/hip_runtime.h>

// GRU: B=32, S=512, D=1024, H=1024
// out = concat(output[B,S,H], h_last[B,H]) f32
#define B_  32
#define S_  512
#define D_  1024
#define H_  1024
#define G3  3072

typedef __attribute__((ext_vector_type(8))) short  short8;   // 8 x bf16 (4 VGPR)
typedef __attribute__((ext_vector_type(4))) float  floatx4;  // MFMA C/D

__device__ __forceinline__ unsigned short f2bf(float f) {
    unsigned int u = __builtin_bit_cast(unsigned int, f);
    u = (u + 0x7FFFu + ((u >> 16) & 1u)) >> 16;
    return (unsigned short)u;
}
__device__ __forceinline__ float bf2f(unsigned short h) {
    unsigned int u = ((unsigned int)h) << 16;
    return __builtin_bit_cast(float, u);
}
// fast sigmoid/tanh via v_exp_f32 + v_rcp_f32 (saturate correctly at +/-inf)
__device__ __forceinline__ float fsigmoid(float x) {
    float e = __builtin_amdgcn_exp2f(-1.4426950408889634f * x);
    return __builtin_amdgcn_rcpf(1.f + e);
}
__device__ __forceinline__ float ftanh(float x) {
    float e = __builtin_amdgcn_exp2f(2.8853900817779268f * x);
    return 1.f - 2.f * __builtin_amdgcn_rcpf(e + 1.f);
}

// ---------------------------------------------------------------------------
// Kernel 0: convert weights f32->bf16 (W_hh hi/lo split), zero h + flags
// ---------------------------------------------------------------------------
__global__ __launch_bounds__(256) void convert_kernel(
    const float* __restrict__ wih, const float* __restrict__ whh,
    unsigned short* __restrict__ wih_h,
    unsigned short* __restrict__ whh_h, unsigned short* __restrict__ whh_l,
    unsigned int* __restrict__ hbuf /* 65536 uints: 2 ping-pong x 32 x 1024 */,
    int* __restrict__ cnt /* 128 ints: [stream][jg] flags */) {
    int tid = blockIdx.x * 256 + threadIdx.x;   // 786432 threads
    int i4 = tid * 4;
    if (i4 < 3145728) {
        float4 w = *(const float4*)(wih + i4);
        ushort4 o;
        o.x = f2bf(w.x); o.y = f2bf(w.y); o.z = f2bf(w.z); o.w = f2bf(w.w);
        *(ushort4*)(wih_h + i4) = o;

        float4 v = *(const float4*)(whh + i4);
        ushort4 h;
        h.x = f2bf(v.x); h.y = f2bf(v.y); h.z = f2bf(v.z); h.w = f2bf(v.w);
        ushort4 l;
        l.x = f2bf(v.x - bf2f(h.x)); l.y = f2bf(v.y - bf2f(h.y));
        l.z = f2bf(v.z - bf2f(h.z)); l.w = f2bf(v.w - bf2f(h.w));
        *(ushort4*)(whh_h + i4) = h;
        *(ushort4*)(whh_l + i4) = l;
    }
    if (tid < 16384) {  // zero both packed h ping-pong buffers
        uint4 z; z.x = z.y = z.z = z.w = 0;
        *(uint4*)(hbuf + tid * 4) = z;
    }
    if (tid < 32) {     // zero the 128 per-producer step flags
        int4 z4; z4.x = z4.y = z4.z = z4.w = 0;
        *(int4*)(cnt + tid * 4) = z4;
    }
}

// ---------------------------------------------------------------------------
// Kernel 1: gi = feats @ W_ih^T + bias_ih   -> bf16 [B*S][3H]  (unchanged)
// ---------------------------------------------------------------------------
#define BM 128
#define BN 128
#define BK 32
#define LDA 40  // padded LDS row: 80B stride -> conflict-free b128 reads

__global__ __launch_bounds__(256, 2) void gi_gemm(
    const float* __restrict__ feats,
    const unsigned short* __restrict__ wih_h,
    const float* __restrict__ bias_ih,
    unsigned short* __restrict__ gi) {
    __shared__ unsigned short As[BM * LDA];
    __shared__ unsigned short Bs[BN * LDA];

    int bx = blockIdx.x;
    int nb = bx % (G3 / BN);          // 24
    int mb = bx / (G3 / BN);          // 128
    int m0 = mb * BM, n0 = nb * BN;
    int tid = threadIdx.x;
    int lane = tid & 63, wave = tid >> 6;
    int quad = lane >> 4, l15 = lane & 15;
    int wm = (wave >> 1) * 64, wn = (wave & 1) * 64;

    floatx4 acc[4][4];
#pragma unroll
    for (int i = 0; i < 4; ++i)
#pragma unroll
        for (int j = 0; j < 4; ++j) acc[i][j] = (floatx4){0.f, 0.f, 0.f, 0.f};

    float bias[4];
#pragma unroll
    for (int j = 0; j < 4; ++j) bias[j] = bias_ih[n0 + wn + j * 16 + l15];

    int srow = tid >> 1, shalf = tid & 1;
    const float* aptr = feats + (size_t)(m0 + srow) * D_ + shalf * 16;
    const unsigned short* bptr = wih_h + (size_t)(n0 + srow) * D_ + shalf * 16;
    unsigned short* as = As + srow * LDA + shalf * 16;
    unsigned short* bs = Bs + srow * LDA + shalf * 16;

    for (int kt = 0; kt < D_ / BK; ++kt) {
        int k0 = kt * BK;
        float4 a0 = *(const float4*)(aptr + k0);
        float4 a1 = *(const float4*)(aptr + k0 + 4);
        float4 a2 = *(const float4*)(aptr + k0 + 8);
        float4 a3 = *(const float4*)(aptr + k0 + 12);
        uint4 bA = *(const uint4*)(bptr + k0);
        uint4 bB = *(const uint4*)(bptr + k0 + 8);

        union { unsigned short u16[16]; uint4 v[2]; } pk;
        pk.u16[0] = f2bf(a0.x);  pk.u16[1] = f2bf(a0.y);
        pk.u16[2] = f2bf(a0.z);  pk.u16[3] = f2bf(a0.w);
        pk.u16[4] = f2bf(a1.x);  pk.u16[5] = f2bf(a1.y);
        pk.u16[6] = f2bf(a1.z);  pk.u16[7] = f2bf(a1.w);
        pk.u16[8] = f2bf(a2.x);  pk.u16[9] = f2bf(a2.y);
        pk.u16[10] = f2bf(a2.z); pk.u16[11] = f2bf(a2.w);
        pk.u16[12] = f2bf(a3.x); pk.u16[13] = f2bf(a3.y);
        pk.u16[14] = f2bf(a3.z); pk.u16[15] = f2bf(a3.w);

        *(uint4*)as = pk.v[0];
        *(uint4*)(as + 8) = pk.v[1];
        *(uint4*)bs = bA;
        *(uint4*)(bs + 8) = bB;
        __syncthreads();

        short8 af[4], bf[4];
#pragma unroll
        for (int i = 0; i < 4; ++i)
            af[i] = *(const short8*)(As + (wm + i * 16 + l15) * LDA + quad * 8);
#pragma unroll
        for (int j = 0; j < 4; ++j)
            bf[j] = *(const short8*)(Bs + (wn + j * 16 + l15) * LDA + quad * 8);
#pragma unroll
        for (int i = 0; i < 4; ++i)
#pragma unroll
            for (int j = 0; j < 4; ++j)
                acc[i][j] = __builtin_amdgcn_mfma_f32_16x16x32_bf16(
                    af[i], bf[j], acc[i][j], 0, 0, 0);
        __syncthreads();
    }

#pragma unroll
    for (int i = 0; i < 4; ++i)
#pragma unroll
        for (int j = 0; j < 4; ++j)
#pragma unroll
            for (int r = 0; r < 4; ++r) {
                int m = m0 + wm + i * 16 + quad * 4 + r;
                int n = n0 + wn + j * 16 + l15;
                gi[(size_t)m * G3 + n] = f2bf(acc[i][j][r] + bias[j]);
            }
}

// ---------------------------------------------------------------------------
// Kernel 2: persistent recurrence — DUAL-STREAM interleave.
// 64 blocks x 512 thr; block jg owns 16 h-cols for BOTH independent batch
// halves (A = rows 0..15, B = rows 16..31). The two streams run half an
// iteration out of phase: stream A's flag poll (wave 4) overlaps stream B's
// finish phase and vice versa, hiding the protocol round trips under the
// other stream's compute. Protocol primitives are verbatim round-4
// (relaxed agent atomics, per-stream flags cnt[2][64], drain-then-flag,
// packed u32 hi|lo h format). out stores staged in LDS, flushed every 4
// steps AFTER the flag (vmcnt pollution off the critical path).
// ---------------------------------------------------------------------------
__global__ __launch_bounds__(512, 2) void gru_rec(
    const unsigned short* __restrict__ gi,
    const unsigned short* __restrict__ whh_h,
    const unsigned short* __restrict__ whh_l,
    const float* __restrict__ bias_hh,
    unsigned int* __restrict__ hbuf,    // [2][32][1024] packed hi|lo
    int* __restrict__ cnt,              // [2][64] flags: [0]=A, [1]=B
    float* __restrict__ out) {
    __shared__ floatx4 partsA[8][3][64];   // 24 KB
    __shared__ floatx4 partsB[8][3][64];   // 24 KB
    __shared__ float sbufA[1024];          // 4 KB: out staging (4 steps)
    __shared__ float sbufB[1024];          // 4 KB

    const int tid = threadIdx.x;
    const int lane = tid & 63, ks = tid >> 6;
    const int quad = lane >> 4, l15 = lane & 15;
    const int jg = blockIdx.x;
    const int j = jg * 16 + l15;

    // preload W_hh fragments (hi+lo): shared by both streams (same cols)
    short8 wfh[3][4], wfl[3][4];
#pragma unroll
    for (int g = 0; g < 3; ++g)
#pragma unroll
        for (int ki = 0; ki < 4; ++ki) {
            size_t off = (size_t)(g * H_ + j) * H_ + ks * 128 + ki * 32 + quad * 8;
            wfh[g][ki] = *(const short8*)(whh_h + off);
            wfl[g][ki] = *(const short8*)(whh_l + off);
        }

    // finish mapping (tid<256): one output (row rr, col cc) per lane, per stream
    const int rr = (tid >> 4) & 15, cc = tid & 15;
    const int browA = rr, browB = 16 + rr;
    const int jc = jg * 16 + cc;
    float bR = 0.f, bZ = 0.f, bN = 0.f;
    float hrA = 0.f, hrB = 0.f;
    if (tid < 256) {
        bR = bias_hh[jc]; bZ = bias_hh[H_ + jc]; bN = bias_hh[2 * H_ + jc];
    }

    int* const fA = cnt;
    int* const fB = cnt + 64;
    const int kbase = ks * 128 + quad * 8;      // uint-col within row of 1024
    const float* const pfA = (const float*)partsA;
    const float* const pfB = (const float*)partsB;

    for (int t = 0; t < S_; ++t) {
        const unsigned int* hc = hbuf + ((t & 1) << 15);
        unsigned int* hn = hbuf + (((t & 1) ^ 1) << 15);

        // ---- P1: gi(t) loads + load hB(t) + MFMA_B --------------------
        unsigned short gAr = 0, gAz = 0, gAn = 0, gBr = 0, gBz = 0, gBn = 0;
        if (tid < 256) {
            const size_t gbA = ((size_t)browA * S_ + t) * G3 + jc;
            const size_t gbB = ((size_t)browB * S_ + t) * G3 + jc;
            gAr = gi[gbA]; gAz = gi[gbA + H_]; gAn = gi[gbA + 2 * H_];
            gBr = gi[gbB]; gBz = gi[gbB + H_]; gBn = gi[gbB + 2 * H_];
        }
        {
            unsigned long long q[16];
            const unsigned long long* p =
                (const unsigned long long*)(hc + (16 + l15) * H_ + kbase);
#pragma unroll
            for (int ki = 0; ki < 4; ++ki)
#pragma unroll
                for (int c = 0; c < 4; ++c)
                    q[ki * 4 + c] = __hip_atomic_load(p + ki * 16 + c,
                                                      __ATOMIC_RELAXED,
                                                      __HIP_MEMORY_SCOPE_AGENT);
            short8 ah[4], al[4];
#pragma unroll
            for (int ki = 0; ki < 4; ++ki) {
                short8 av, lv;
#pragma unroll
                for (int c = 0; c < 4; ++c) {
                    unsigned long long qq = q[ki * 4 + c];
                    unsigned int u0 = (unsigned int)qq;
                    unsigned int u1 = (unsigned int)(qq >> 32);
                    av[2 * c]     = (short)(u0 & 0xffffu);
                    av[2 * c + 1] = (short)(u1 & 0xffffu);
                    lv[2 * c]     = (short)(u0 >> 16);
                    lv[2 * c + 1] = (short)(u1 >> 16);
                }
                ah[ki] = av; al[ki] = lv;
            }
            floatx4 acc[3];
#pragma unroll
            for (int g = 0; g < 3; ++g) acc[g] = (floatx4){0.f, 0.f, 0.f, 0.f};
#pragma unroll
            for (int ki = 0; ki < 4; ++ki)
#pragma unroll
                for (int g = 0; g < 3; ++g) {
                    acc[g] = __builtin_amdgcn_mfma_f32_16x16x32_bf16(ah[ki], wfh[g][ki], acc[g], 0, 0, 0);
                    acc[g] = __builtin_amdgcn_mfma_f32_16x16x32_bf16(ah[ki], wfl[g][ki], acc[g], 0, 0, 0);
                    acc[g] = __builtin_amdgcn_mfma_f32_16x16x32_bf16(al[ki], wfh[g][ki], acc[g], 0, 0, 0);
                }
#pragma unroll
            for (int g = 0; g < 3; ++g) partsB[ks][g][lane] = acc[g];
        }
        __syncthreads();   // bar1: partsB ready

        // ---- P2: finish B (tid<256) | wave4 polls A(t) ----------------
        if (ks == 4) {     // poll stream-A flags (one per lane)
            int v = __hip_atomic_load(fA + lane, __ATOMIC_RELAXED,
                                      __HIP_MEMORY_SCOPE_AGENT);
            while (!__all(v >= t)) {
                __builtin_amdgcn_s_sleep(1);
                v = __hip_atomic_load(fA + lane, __ATOMIC_RELAXED,
                                      __HIP_MEMORY_SCOPE_AGENT);
            }
        }
        if (tid < 256) {
            const int lidx = ((rr >> 2) * 16 + cc);
            const int r4 = rr & 3;
            float gh0 = 0.f, gh1 = 0.f, gh2 = 0.f;
#pragma unroll
            for (int w = 0; w < 8; ++w) {
                gh0 += pfB[(((w * 3 + 0) * 64 + lidx) << 2) + r4];
                gh1 += pfB[(((w * 3 + 1) * 64 + lidx) << 2) + r4];
                gh2 += pfB[(((w * 3 + 2) * 64 + lidx) << 2) + r4];
            }
            const float rg = fsigmoid(bf2f(gBr) + gh0 + bR);
            const float zg = fsigmoid(bf2f(gBz) + gh1 + bZ);
            const float ng = ftanh(bf2f(gBn) + rg * (gh2 + bN));
            const float hy = ng + zg * (hrB - ng);
            hrB = hy;
            const unsigned short hh = f2bf(hy);
            const unsigned int pk = (unsigned int)hh |
                                    ((unsigned int)f2bf(hy - bf2f(hh)) << 16);
            __hip_atomic_store(hn + browB * H_ + jc, pk, __ATOMIC_RELAXED,
                               __HIP_MEMORY_SCOPE_AGENT);
            asm volatile("s_waitcnt vmcnt(0)" ::: "memory");
            if (tid == 0)
                __hip_atomic_store(fB + jg, t + 1, __ATOMIC_RELAXED,
                                   __HIP_MEMORY_SCOPE_AGENT);
            sbufB[(t & 3) * 256 + tid] = hy;
            if ((t & 3) == 3) {
#pragma unroll
                for (int i = 0; i < 4; ++i)
                    __builtin_nontemporal_store(sbufB[i * 256 + tid],
                        out + ((size_t)browB * S_ + (t - 3 + i)) * H_ + jc);
            }
            if (t == S_ - 1)
                __builtin_nontemporal_store(hrB,
                    out + (size_t)B_ * S_ * H_ + (size_t)browB * H_ + jc);
        }
        __syncthreads();   // bar2: pollA passed; safe to load hA

        // ---- P3: load hA(t) + MFMA_A ----------------------------------
        {
            unsigned long long q[16];
            const unsigned long long* p =
                (const unsigned long long*)(hc + l15 * H_ + kbase);
#pragma unroll
            for (int ki = 0; ki < 4; ++ki)
#pragma unroll
                for (int c = 0; c < 4; ++c)
                    q[ki * 4 + c] = __hip_atomic_load(p + ki * 16 + c,
                                                      __ATOMIC_RELAXED,
                                                      __HIP_MEMORY_SCOPE_AGENT);
            short8 ah[4], al[4];
#pragma unroll
            for (int ki = 0; ki < 4; ++ki) {
                short8 av, lv;
#pragma unroll
                for (int c = 0; c < 4; ++c) {
                    unsigned long long qq = q[ki * 4 + c];
                    unsigned int u0 = (unsigned int)qq;
                    unsigned int u1 = (unsigned int)(qq >> 32);
                    av[2 * c]     = (short)(u0 & 0xffffu);
                    av[2 * c + 1] = (short)(u1 & 0xffffu);
                    lv[2 * c]     = (short)(u0 >> 16);
                    lv[2 * c + 1] = (short)(u1 >> 16);
                }
                ah[ki] = av; al[ki] = lv;
            }
            floatx4 acc[3];
#pragma unroll
            for (int g = 0; g < 3; ++g) acc[g] = (floatx4){0.f, 0.f, 0.f, 0.f};
#pragma unroll
            for (int ki = 0; ki < 4; ++ki)
#pragma unroll
                for (int g = 0; g < 3; ++g) {
                    acc[g] = __builtin_amdgcn_mfma_f32_16x16x32_bf16(ah[ki], wfh[g][ki], acc[g], 0, 0, 0);
                    acc[g] = __builtin_amdgcn_mfma_f32_16x16x32_bf16(ah[ki], wfl[g][ki], acc[g], 0, 0, 0);
                    acc[g] = __builtin_amdgcn_mfma_f32_16x16x32_bf16(al[ki], wfh[g][ki], acc[g], 0, 0, 0);
                }
#pragma unroll
            for (int g = 0; g < 3; ++g) partsA[ks][g][lane] = acc[g];
        }
        __syncthreads();   // bar3: partsA ready

        // ---- P4: finish A (tid<256) | wave4 polls B(t+1) --------------
        if (ks == 4 && t + 1 < S_) {   // poll stream-B flags for next iter
            int v = __hip_atomic_load(fB + lane, __ATOMIC_RELAXED,
                                      __HIP_MEMORY_SCOPE_AGENT);
            while (!__all(v >= t + 1)) {
                __builtin_amdgcn_s_sleep(1);
                v = __hip_atomic_load(fB + lane, __ATOMIC_RELAXED,
                                      __HIP_MEMORY_SCOPE_AGENT);
            }
        }
        if (tid < 256) {
            const int lidx = ((rr >> 2) * 16 + cc);
            const int r4 = rr & 3;
            float gh0 = 0.f, gh1 = 0.f, gh2 = 0.f;
#pragma unroll
            for (int w = 0; w < 8; ++w) {
                gh0 += pfA[(((w * 3 + 0) * 64 + lidx) << 2) + r4];
                gh1 += pfA[(((w * 3 + 1) * 64 + lidx) << 2) + r4];
                gh2 += pfA[(((w * 3 + 2) * 64 + lidx) << 2) + r4];
            }
            const float rg = fsigmoid(bf2f(gAr) + gh0 + bR);
            const float zg = fsigmoid(bf2f(gAz) + gh1 + bZ);
            const float ng = ftanh(bf2f(gAn) + rg * (gh2 + bN));
            const float hy = ng + zg * (hrA - ng);
            hrA = hy;
            const unsigned short hh = f2bf(hy);
            const unsigned int pk = (unsigned int)hh |
                                    ((unsigned int)f2bf(hy - bf2f(hh)) << 16);
            __hip_atomic_store(hn + browA * H_ + jc, pk, __ATOMIC_RELAXED,
                               __HIP_MEMORY_SCOPE_AGENT);
            asm volatile("s_waitcnt vmcnt(0)" ::: "memory");
            if (tid == 0)
                __hip_atomic_store(fA + jg, t + 1, __ATOMIC_RELAXED,
                                   __HIP_MEMORY_SCOPE_AGENT);
            sbufA[(t & 3) * 256 + tid] = hy;
            if ((t & 3) == 3) {
#pragma unroll
                for (int i = 0; i < 4; ++i)
                    __builtin_nontemporal_store(sbufA[i * 256 + tid],
                        out + ((size_t)browA * S_ + (t - 3 + i)) * H_ + jc);
            }
            if (t == S_ - 1)
                __builtin_nontemporal_store(hrA,
                    out + (size_t)B_ * S_ * H_ + (size_t)browA * H_ + jc);
        }
        __syncthreads();   // bar4: pollB(t+1) passed; next iter may load hB
    }
}

// ---------------------------------------------------------------------------
extern "C" void kernel_launch(void* const* d_in, const int* in_sizes, int n_in,
                              void* d_out, int out_size, void* d_ws, size_t ws_size,
                              hipStream_t stream) {
    const float* feats = (const float*)d_in[0];
    const float* wih   = (const float*)d_in[1];
    const float* whh   = (const float*)d_in[2];
    const float* bih   = (const float*)d_in[3];
    const float* bhh   = (const float*)d_in[4];
    float* out = (float*)d_out;

    // ws layout (ushorts): wih_h | whh_h | whh_l | gi | hbuf(u32) | cnt
    unsigned short* wih_h = (unsigned short*)d_ws;
    unsigned short* whh_h = wih_h + (size_t)3145728;
    unsigned short* whh_l = whh_h + (size_t)3145728;
    unsigned short* gi    = whh_l + (size_t)3145728;
    unsigned int*   hbuf  = (unsigned int*)(gi + (size_t)16384 * G3);
    int*            cnt   = (int*)(hbuf + 65536);

    hipLaunchKernelGGL(convert_kernel, dim3(3072), dim3(256), 0, stream,
                       wih, whh, wih_h, whh_h, whh_l, hbuf, cnt);
    hipLaunchKernelGGL(gi_gemm, dim3(3072), dim3(256), 0, stream,
                       feats, wih_h, bih, gi);

    void* args[] = {(void*)&gi, (void*)&whh_h, (void*)&whh_l,
                    (void*)&bhh, (void*)&hbuf, (void*)&cnt, (void*)&out};
    hipLaunchCooperativeKernel((const void*)gru_rec, dim3(64), dim3(512),
                               args, 0, stream);
}